// Round 1
// 414.274 us; speedup vs baseline: 1.0261x; 1.0261x over previous
//
#include <hip/hip_runtime.h>
#include <hip/hip_bf16.h>

#define BB 32
#define SS 4096
#define HH 512
#define EE 512
#define NCH 64          // 64-row s-chunks per b
#define NEGV -1000000000.0f

using float4v = __attribute__((ext_vector_type(4))) float;
using short8v = __attribute__((ext_vector_type(8))) short;

#if defined(__has_builtin)
#if __has_builtin(__builtin_amdgcn_sched_barrier)
#define SCHED_FENCE() __builtin_amdgcn_sched_barrier(0)
#endif
#if __has_builtin(__builtin_amdgcn_rcpf)
#define FAST_RCP(x) __builtin_amdgcn_rcpf(x)
#endif
#if __has_builtin(__builtin_amdgcn_s_setprio)
#define SETPRIO(n) __builtin_amdgcn_s_setprio(n)
#endif
#endif
#ifndef SCHED_FENCE
#define SCHED_FENCE()
#endif
#ifndef FAST_RCP
#define FAST_RCP(x) (1.0f / (x))
#endif
#ifndef SETPRIO
#define SETPRIO(n)
#endif

__device__ inline unsigned short f2bf(float x) {
    union { float f; unsigned int u; } c; c.f = x;
    unsigned int r = c.u + 0x7FFFu + ((c.u >> 16) & 1u);  // RNE
    return (unsigned short)(r >> 16);
}
__device__ inline float bf2f(unsigned short s) {
    union { float f; unsigned int u; } c; c.u = ((unsigned int)s) << 16;
    return c.f;
}
__device__ inline unsigned int pk2bf(float a, float b) {  // packed RNE cvt
    union { __hip_bfloat162 h; unsigned int u; } c;
    c.h = __float22bfloat162_rn(float2{a, b});
    return c.u;
}

// Merged prep: blocks [0,128) compute split-K q-projection partials (no atomics,
// no memset); blocks [128,256) repack Wk (E,H) fp32 -> fragment-linear bf16.
__global__ void prep_kernel(const float* __restrict__ query, const float* __restrict__ Wq,
                            float* __restrict__ qp4,
                            const float* __restrict__ Wk, unsigned short* __restrict__ WkT) {
    int bx = blockIdx.x, t = threadIdx.x;  // 256 threads
    if (bx < 4 * BB) {
        __shared__ float qs[128];
        int b = bx >> 2, seg = bx & 3;
        if (t < 128) qs[t] = query[b * HH + seg * 128 + t];
        __syncthreads();
        float a0 = 0.f, a1 = 0.f;
        const float* wq = Wq + (size_t)(seg * 128) * HH;
        #pragma unroll 8
        for (int e = 0; e < 128; ++e) {
            float q = qs[e];
            a0 += q * wq[(size_t)e * HH + t];
            a1 += q * wq[(size_t)e * HH + t + 256];
        }
        qp4[((size_t)seg * BB + b) * HH + t] = a0;
        qp4[((size_t)seg * BB + b) * HH + t + 256] = a1;
    } else {
        int g = (bx - 4 * BB) * 256 + t;
        int lane = g & 63, nt = (g >> 6) & 31, ks = g >> 11;
        int lq = lane >> 4, lr = lane & 15;
        int h = nt * 16 + lr;
        int e0 = ks * 32 + lq * 8;
        short8v o;
        #pragma unroll
        for (int j = 0; j < 8; ++j) o[j] = (short)f2bf(Wk[(size_t)(e0 + j) * HH + h]);
        *(short8v*)(WkT + (size_t)g * 8) = o;
    }
}

// Fused scores + online-softmax stats + context partial. grid (NCH, B), 512 thr.
// Keys tile staged in four 128-col segments (next segment's HBM loads issued and
// fence-pinned before this segment's MFMAs). WkT fragments are register
// double-buffered one k-slice ahead so their L2 latency hides under the MFMAs.
__launch_bounds__(512, 4)
__global__ void fused_kernel(const float* __restrict__ keys, const unsigned short* __restrict__ WkT,
                             const float* __restrict__ qp4, const float* __restrict__ bq,
                             const float* __restrict__ bk, const float* __restrict__ v,
                             const float* __restrict__ bv, const int* __restrict__ mask,
                             float* __restrict__ pe_out, float* __restrict__ part,
                             float* __restrict__ marr, float* __restrict__ larr) {
    constexpr int LDK = EE + 8;                 // 520 shorts, 1040B row stride
    __shared__ unsigned short klds[64 * LDK];   // 66.5 KB
    __shared__ float qp_lds[HH];
    __shared__ float v_lds[HH];
    __shared__ float red[8][64];
    __shared__ float p_lds[64];
    int b = blockIdx.y, c = blockIdx.x, s0 = c * 64;
    int tid = threadIdx.x;

    // issue segment-0 keys loads first (earliest HBM), then small L2 reads
    const float4v* ksrc = (const float4v*)(keys + ((size_t)b * SS + s0) * EE);
    float4v kv[4];
    #pragma unroll
    for (int p = 0; p < 4; ++p) {
        int idx = tid + p * 512;
        kv[p] = ksrc[(size_t)(idx >> 5) * 128 + (idx & 31)];
    }
    int mval = 0;
    if (tid < 64) mval = mask[b * SS + s0 + tid];  // prefetch; used at the end

    for (int i = tid; i < HH; i += 512) {
        qp_lds[i] = qp4[((size_t)0 * BB + b) * HH + i] + qp4[((size_t)1 * BB + b) * HH + i]
                  + qp4[((size_t)2 * BB + b) * HH + i] + qp4[((size_t)3 * BB + b) * HH + i]
                  + bq[i] + bk[i];
        v_lds[i] = v[i];
    }

    #pragma unroll
    for (int p = 0; p < 4; ++p) {
        int idx = tid + p * 512, row = idx >> 5, c4 = idx & 31;
        unsigned int u0 = pk2bf(kv[p].x, kv[p].y), u1 = pk2bf(kv[p].z, kv[p].w);
        *(uint2*)(&klds[row * LDK + c4 * 4]) = make_uint2(u0, u1);
    }

    int w = tid >> 6, lane = tid & 63;
    int lq = lane >> 4, lr = lane & 15;
    int nt0 = w * 4;
    const short8v* Wf = (const short8v*)WkT;

    // preload k-slice 0's B fragments before the barrier (overlaps barrier wait)
    short8v bcur[4];
    #pragma unroll
    for (int j = 0; j < 4; ++j) bcur[j] = Wf[(size_t)(nt0 + j) * 64 + lane];

    float4v acc[4][4];
    #pragma unroll
    for (int m = 0; m < 4; ++m)
        #pragma unroll
        for (int j = 0; j < 4; ++j) acc[m][j] = (float4v){0.f, 0.f, 0.f, 0.f};

    __syncthreads();

    #pragma unroll
    for (int q = 0; q < 4; ++q) {
        if (q < 3) {  // issue next segment's HBM loads; fence pins them above the MFMAs
            #pragma unroll
            for (int p = 0; p < 4; ++p) {
                int idx = tid + p * 512;
                kv[p] = ksrc[(size_t)(idx >> 5) * 128 + (q + 1) * 32 + (idx & 31)];
            }
        }
        SCHED_FENCE();
        #pragma unroll
        for (int ksl = 0; ksl < 4; ++ksl) {
            int kq = q * 4 + ksl;
            short8v bn[4];
            if (kq < 15) {  // prefetch next k-slice's B fragments (compile-time guard)
                #pragma unroll
                for (int j = 0; j < 4; ++j)
                    bn[j] = Wf[((size_t)(kq + 1) * 32 + nt0 + j) * 64 + lane];
            }
            SETPRIO(1);
            #pragma unroll
            for (int m = 0; m < 4; ++m) {
                short8v afrag = *(const short8v*)(&klds[(m * 16 + lr) * LDK + kq * 32 + lq * 8]);
                #pragma unroll
                for (int j = 0; j < 4; ++j)
                    acc[m][j] = __builtin_amdgcn_mfma_f32_16x16x32_bf16(afrag, bcur[j], acc[m][j], 0, 0, 0);
            }
            SETPRIO(0);
            if (kq < 15) {
                #pragma unroll
                for (int j = 0; j < 4; ++j) bcur[j] = bn[j];
            }
        }
        if (q < 3) {  // cvt+store next segment (LDS range disjoint from this segment's reads)
            #pragma unroll
            for (int p = 0; p < 4; ++p) {
                int idx = tid + p * 512, row = idx >> 5, c4 = (q + 1) * 32 + (idx & 31);
                unsigned int u0 = pk2bf(kv[p].x, kv[p].y), u1 = pk2bf(kv[p].z, kv[p].w);
                *(uint2*)(&klds[row * LDK + c4 * 4]) = make_uint2(u0, u1);
            }
            __syncthreads();
        }
    }

    // tanh epilogue: part += v[h] - 2 v[h] / (e^{2x}+1)   (== v[h]*tanh(x), clamp-free)
    // fast v_rcp_f32: rel err ~1e-7 on |tanh|<=1, negligible vs 4.9e-4 tolerance
    float part_r[4][4];
    #pragma unroll
    for (int m = 0; m < 4; ++m)
        #pragma unroll
        for (int r = 0; r < 4; ++r) part_r[m][r] = 0.f;
    #pragma unroll
    for (int j = 0; j < 4; ++j) {
        int h = (nt0 + j) * 16 + lr;
        float vj = v_lds[h], qj = qp_lds[h], vj2 = -2.f * vj;
        #pragma unroll
        for (int m = 0; m < 4; ++m) {
            #pragma unroll
            for (int r = 0; r < 4; ++r) {
                float x = qj + acc[m][j][r];
                float rr = FAST_RCP(__expf(x + x) + 1.f);
                part_r[m][r] += __builtin_fmaf(vj2, rr, vj);
            }
        }
    }
    #pragma unroll
    for (int m = 0; m < 4; ++m)
        #pragma unroll
        for (int r = 0; r < 4; ++r) {
            float p = part_r[m][r];
            p += __shfl_xor(p, 1, 16);
            p += __shfl_xor(p, 2, 16);
            p += __shfl_xor(p, 4, 16);
            p += __shfl_xor(p, 8, 16);
            part_r[m][r] = p;
        }
    if (lr == 0) {
        #pragma unroll
        for (int m = 0; m < 4; ++m)
            #pragma unroll
            for (int r = 0; r < 4; ++r)
                red[w][m * 16 + lq * 4 + r] = part_r[m][r];
    }
    __syncthreads();

    // wave 0: final score, mask, chunk-local softmax stats; store pe (not raw score)
    if (tid < 64) {
        float sc = red[0][tid] + red[1][tid] + red[2][tid] + red[3][tid]
                 + red[4][tid] + red[5][tid] + red[6][tid] + red[7][tid] + bv[0];
        if (mval == 0) sc = NEGV;
        float mv = sc;
        #pragma unroll
        for (int off = 1; off < 64; off <<= 1) mv = fmaxf(mv, __shfl_xor(mv, off));
        float pe = __expf(sc - mv);
        float ls = pe;
        #pragma unroll
        for (int off = 1; off < 64; off <<= 1) ls += __shfl_xor(ls, off);
        p_lds[tid] = pe;
        pe_out[b * SS + s0 + tid] = pe;
        if (tid == 0) { marr[b * NCH + c] = mv; larr[b * NCH + c] = ls; }
    }
    __syncthreads();

    // context partial from the retained LDS tile: o[e] = sum_s p[s]*keys[s][e]
    {
        float o0 = 0.f, o1 = 0.f;
        #pragma unroll 8
        for (int s = 0; s < 32; ++s) {
            o0 += p_lds[s]      * bf2f(klds[s * LDK + tid]);
            o1 += p_lds[s + 32] * bf2f(klds[(s + 32) * LDK + tid]);
        }
        part[((size_t)b * NCH + c) * EE + tid] = o0 + o1;
    }
}

// Merge chunk partials; grid (4, B): x==0 writes ctx, all x write attn slices.
// attn[s] = pe[s] * exp(m_chunk - M) / L  (identical math, no re-exp of scores)
__global__ void finalize_kernel(const float* __restrict__ pe_arr, const float* __restrict__ part,
                                const float* __restrict__ marr, const float* __restrict__ larr,
                                float* __restrict__ ctx, float* __restrict__ attn) {
    __shared__ float wgt[NCH];
    __shared__ float Ls;
    int b = blockIdx.y, px = blockIdx.x, t = threadIdx.x;  // 512 threads
    if (t < NCH) {
        float m = marr[b * NCH + t], l = larr[b * NCH + t];
        float M = m;
        #pragma unroll
        for (int off = 1; off < 64; off <<= 1) M = fmaxf(M, __shfl_xor(M, off));
        float wq = __expf(m - M);
        float L = wq * l;
        #pragma unroll
        for (int off = 1; off < 64; off <<= 1) L += __shfl_xor(L, off);
        wgt[t] = wq;
        if (t == 0) Ls = L;
    }
    __syncthreads();
    float invL = 1.f / Ls;
    if (px == 0) {
        float o = 0.f;
        #pragma unroll 8
        for (int cc = 0; cc < NCH; ++cc)
            o += wgt[cc] * part[((size_t)b * NCH + cc) * EE + t];
        ctx[b * EE + t] = o * invL;
    }
    int s0 = px * 1024;
    attn[b * SS + s0 + t]       = pe_arr[b * SS + s0 + t]       * wgt[(s0 + t) >> 6]       * invL;
    attn[b * SS + s0 + t + 512] = pe_arr[b * SS + s0 + t + 512] * wgt[(s0 + t + 512) >> 6] * invL;
}

extern "C" void kernel_launch(void* const* d_in, const int* in_sizes, int n_in,
                              void* d_out, int out_size, void* d_ws, size_t ws_size,
                              hipStream_t stream) {
    const float* query = (const float*)d_in[0];
    const float* keys  = (const float*)d_in[1];
    const int*   mask  = (const int*)d_in[2];
    const float* Wq    = (const float*)d_in[3];
    const float* bq    = (const float*)d_in[4];
    const float* Wk    = (const float*)d_in[5];
    const float* bk    = (const float*)d_in[6];
    const float* v     = (const float*)d_in[7];
    const float* bv    = (const float*)d_in[8];

    float* out  = (float*)d_out;
    float* ctx  = out;            // (B, E)
    float* attn = out + BB * EE;  // (B, S)

    char* ws = (char*)d_ws;
    float* qp4          = (float*)ws;                         // 4*32*512*4 = 262144 B
    unsigned short* WkT = (unsigned short*)(ws + 262144);     // 524288 B
    float* pe           = (float*)(ws + 786432);              // 524288 B
    float* part         = (float*)(ws + 1310720);             // 4194304 B
    float* marr         = (float*)(ws + 5505024);             // 8192 B
    float* larr         = (float*)(ws + 5513216);             // 8192 B

    prep_kernel<<<256, 256, 0, stream>>>(query, Wq, qp4, Wk, WkT);
    fused_kernel<<<dim3(NCH, BB), 512, 0, stream>>>(keys, WkT, qp4, bq, bk, v, bv, mask,
                                                    pe, part, marr, larr);
    finalize_kernel<<<dim3(4, BB), 512, 0, stream>>>(pe, part, marr, larr, ctx, attn);
}